// Round 18
// baseline (256.646 us; speedup 1.0000x reference)
//
#include <hip/hip_runtime.h>
#include <cmath>

#define NB 256   // batch
#define NT 512   // seq len
#define ND 50    // emb dim
#define NH 50    // hidden
#define NC 5     // classes

typedef float f32x4 __attribute__((ext_vector_type(4)));
typedef float f32x2 __attribute__((ext_vector_type(2)));

__device__ __forceinline__ float rcpf(float x) { return __builtin_amdgcn_rcpf(x); }
// readlane: uniform result -> SGPR; lane index compile-time const
__device__ __forceinline__ float rdl(float v, int l) {
    return __int_as_float(__builtin_amdgcn_readlane(__float_as_int(v), l));
}
// asm loads: non-rematerializable. ONLY on 16B-aligned addresses (52-float padded rows).
__device__ __forceinline__ void gload4(f32x4& d, const float* p) {
    asm volatile("global_load_dwordx4 %0, %1, off" : "=v"(d) : "v"(p));
}

#define FENCE_BAR                                             \
    asm volatile("s_waitcnt lgkmcnt(0)" ::: "memory");        \
    __builtin_amdgcn_s_barrier();                             \
    asm volatile("" ::: "memory");

// ---------------- K0: repack weights into padded [200][52] rows (16B-aligned) ------------
__global__ __launch_bounds__(256)
void k0_prep(const float* __restrict__ W_hh, const float* __restrict__ W_ih,
             float* __restrict__ wsWih, float* __restrict__ wsWhh)
{
    int idx = blockIdx.x * 256 + threadIdx.x;
    if (idx < 200 * 52) {
        int d = idx / 52, c = idx - (idx / 52) * 52;
        wsWih[idx] = (c < ND) ? W_ih[d * ND + c] : 0.f;
    } else if (idx < 2 * 200 * 52) {
        int j = idx - 200 * 52;
        int d = j / 52, c = j - (j / 52) * 52;
        wsWhh[j] = (c < NH) ? W_hh[d * NH + c] : 0.f;
    }
}

#define DECLROW(P) f32x4 P##_0{},P##_1{},P##_2{},P##_3{},P##_4{},P##_5{},P##_6{},P##_7{}, \
                         P##_8{},P##_9{},P##_10{},P##_11{},P##_12{};
#define LOADROW(P,B) { const float* b_=(B); \
    gload4(P##_0,b_+0);  gload4(P##_1,b_+4);  gload4(P##_2,b_+8);  gload4(P##_3,b_+12); \
    gload4(P##_4,b_+16); gload4(P##_5,b_+20); gload4(P##_6,b_+24); gload4(P##_7,b_+28); \
    gload4(P##_8,b_+32); gload4(P##_9,b_+36); gload4(P##_10,b_+40); gload4(P##_11,b_+44); \
    gload4(P##_12,b_+48); }

// ---------------- K1: scalar-broadcast xp + in-flight pooling partials -------------------
// Per-row gemv chains bitwise == R16/R17. Pooling: threads 200-249 own dim d, accumulate
// per-tile sum/max in t-order (independent of recurrence; hidden under gemv latency).
#define FMA2(H,W,A) __builtin_elementwise_fma((H),(W),(A))
#define KP2(J) { f32x2 a_=e0[2*(J)], b_=e0[2*(J)+1], c_=e1[2*(J)], d_=e1[2*(J)+1]; \
    A01=FMA2(a_,w##J.xy,A01); A23=FMA2(b_,w##J.zw,A23);                            \
    B01=FMA2(c_,w##J.xy,B01); B23=FMA2(d_,w##J.zw,B23); }

__global__ __launch_bounds__(256)
void k1_xproj(const int* __restrict__ x, const int* __restrict__ lengths,
              const float* __restrict__ emb_table,
              const float* __restrict__ wsWih, const float* __restrict__ b_ih,
              const float* __restrict__ b_hh,
              float* __restrict__ xp, float* __restrict__ pool,
              int t0, int t1, int tiles, int tcAlloc, int fullPool)
{
    const int b    = blockIdx.x / tiles;
    const int tile = blockIdx.x % tiles;
    const int rt0  = t0 + tile * 64;
    if (rt0 >= t1) return;
    if (!fullPool && rt0 >= lengths[b]) return;   // legacy skip (fallback mode only)
    const int nrows = min(64, t1 - rt0);

    const int tid = threadIdx.x;
    const int* xrow = x + (size_t)b * NT + rt0;        // uniform base
    const bool doGemv = (tid < 200) && (rt0 < lengths[b]);
    const bool doPool = fullPool && (tid >= 200) && (tid < 250);
    const int  pd = tid - 200;

    float bsum = 0.f;
    const float* wrow = wsWih + tid * 52;
    f32x4 w0{},w1{},w2{},w3{},w4{},w5{},w6{},w7{},w8{},w9{},w10{},w11{},w12{};
    gload4(w0,wrow+0); gload4(w1,wrow+4); gload4(w2,wrow+8); gload4(w3,wrow+12);
    gload4(w4,wrow+16); gload4(w5,wrow+20); gload4(w6,wrow+24); gload4(w7,wrow+28);
    gload4(w8,wrow+32); gload4(w9,wrow+36); gload4(w10,wrow+40); gload4(w11,wrow+44);
    gload4(w12,wrow+48);
    if (tid < 200) bsum = b_ih[tid] + b_hh[tid];
    asm volatile("s_waitcnt vmcnt(0)" ::: "memory");  // weights resident
    __builtin_amdgcn_sched_barrier(0);

    const int wr = 4 * ((tid % NH)) + (tid / NH);     // quad-permuted position (tid<200 use)
    float* xpb = xp + ((size_t)b * tcAlloc + (rt0 - t0)) * 200 + wr;
    float ps = 0.f, pm = -INFINITY;

    int xr0 = __builtin_amdgcn_readfirstlane(xrow[0]);
    int xr1 = __builtin_amdgcn_readfirstlane(xrow[1]);
    for (int row = 0; row < nrows; row += 2) {
        const f32x2* e0 = (const f32x2*)(emb_table + (size_t)xr0 * ND); // 8B-aligned
        const f32x2* e1 = (const f32x2*)(emb_table + (size_t)xr1 * ND);
        const int nr = (row + 2 < nrows) ? row + 2 : 0;   // wrap: harmless re-read
        int nx0 = __builtin_amdgcn_readfirstlane(xrow[nr]);
        int nx1 = __builtin_amdgcn_readfirstlane(xrow[nr + 1]);
        if (doGemv) {
            f32x2 A01 = {bsum, 0.f}, A23 = {0.f, 0.f};
            f32x2 B01 = {bsum, 0.f}, B23 = {0.f, 0.f};
            KP2(0) KP2(1) KP2(2) KP2(3) KP2(4) KP2(5)
            KP2(6) KP2(7) KP2(8) KP2(9) KP2(10) KP2(11)
            A01 = FMA2(e0[24], w12.xy, A01);          // tail: e48->a0, e49->a1
            B01 = FMA2(e1[24], w12.xy, B01);
            xpb[(size_t)row * 200]       = (A01.x + A01.y) + (A23.x + A23.y);
            xpb[(size_t)(row + 1) * 200] = (B01.x + B01.y) + (B23.x + B23.y);
        }
        if (doPool) {                                  // t-order: row, row+1
            float ev0 = emb_table[(size_t)xr0 * ND + pd];
            float ev1 = emb_table[(size_t)xr1 * ND + pd];
            ps = ps + ev0; pm = fmaxf(pm, ev0);
            ps = ps + ev1; pm = fmaxf(pm, ev1);
        }
        xr0 = nx0; xr1 = nx1;
    }
    if (doPool) {
        const int ta = rt0 >> 6;                       // absolute tile id (fullPool: exact)
        float* poolS = pool;
        float* poolM = pool + (size_t)NB * 8 * 64;
        poolS[((size_t)b * 8 + ta) * 64 + pd] = ps;
        poolM[((size_t)b * 8 + ta) * 64 + pd] = pm;
    }
}

// ---------------- K2: 4 waves x 1 gate/lane (R13 verbatim) + O(1) fused epilogue ---------
#define CDOT1(SEED,OUT) { f32x2 A01 = {(SEED), 0.f}, A23 = {0.f, 0.f};        \
    A01=FMA2(hp0 ,CW_0.xy ,A01); A23=FMA2(hp1 ,CW_0.zw ,A23);                 \
    A01=FMA2(hp2 ,CW_1.xy ,A01); A23=FMA2(hp3 ,CW_1.zw ,A23);                 \
    A01=FMA2(hp4 ,CW_2.xy ,A01); A23=FMA2(hp5 ,CW_2.zw ,A23);                 \
    A01=FMA2(hp6 ,CW_3.xy ,A01); A23=FMA2(hp7 ,CW_3.zw ,A23);                 \
    A01=FMA2(hp8 ,CW_4.xy ,A01); A23=FMA2(hp9 ,CW_4.zw ,A23);                 \
    A01=FMA2(hp10,CW_5.xy ,A01); A23=FMA2(hp11,CW_5.zw ,A23);                 \
    A01=FMA2(hp12,CW_6.xy ,A01); A23=FMA2(hp13,CW_6.zw ,A23);                 \
    A01=FMA2(hp14,CW_7.xy ,A01); A23=FMA2(hp15,CW_7.zw ,A23);                 \
    A01=FMA2(hp16,CW_8.xy ,A01); A23=FMA2(hp17,CW_8.zw ,A23);                 \
    A01=FMA2(hp18,CW_9.xy ,A01); A23=FMA2(hp19,CW_9.zw ,A23);                 \
    A01=FMA2(hp20,CW_10.xy,A01); A23=FMA2(hp21,CW_10.zw,A23);                 \
    A01=FMA2(hp22,CW_11.xy,A01); A23=FMA2(hp23,CW_11.zw,A23);                 \
    A23=FMA2(hp24,CW_12.xy,A23);                                              \
    OUT = (A01.x + A01.y) + (A23.x + A23.y); }

#define SSTEP(XQ, S) {                                                        \
    f32x2 hp0 ={rdl(hv,0 ),rdl(hv,1 )}, hp1 ={rdl(hv,2 ),rdl(hv,3 )};         \
    f32x2 hp2 ={rdl(hv,4 ),rdl(hv,5 )}, hp3 ={rdl(hv,6 ),rdl(hv,7 )};         \
    f32x2 hp4 ={rdl(hv,8 ),rdl(hv,9 )}, hp5 ={rdl(hv,10),rdl(hv,11)};         \
    f32x2 hp6 ={rdl(hv,12),rdl(hv,13)}, hp7 ={rdl(hv,14),rdl(hv,15)};         \
    f32x2 hp8 ={rdl(hv,16),rdl(hv,17)}, hp9 ={rdl(hv,18),rdl(hv,19)};         \
    f32x2 hp10={rdl(hv,20),rdl(hv,21)}, hp11={rdl(hv,22),rdl(hv,23)};         \
    f32x2 hp12={rdl(hv,24),rdl(hv,25)}, hp13={rdl(hv,26),rdl(hv,27)};         \
    f32x2 hp14={rdl(hv,28),rdl(hv,29)}, hp15={rdl(hv,30),rdl(hv,31)};         \
    f32x2 hp16={rdl(hv,32),rdl(hv,33)}, hp17={rdl(hv,34),rdl(hv,35)};         \
    f32x2 hp18={rdl(hv,36),rdl(hv,37)}, hp19={rdl(hv,38),rdl(hv,39)};         \
    f32x2 hp20={rdl(hv,40),rdl(hv,41)}, hp21={rdl(hv,42),rdl(hv,43)};         \
    f32x2 hp22={rdl(hv,44),rdl(hv,45)}, hp23={rdl(hv,46),rdl(hv,47)};         \
    f32x2 hp24={rdl(hv,48),rdl(hv,49)};                                       \
    float gg;                                                                 \
    CDOT1(XQ, gg)                                                             \
    { int sn_ = (S) + 4; if (sn_ > nsteps - 1) sn_ = nsteps - 1;              \
      XQ = xpb[(size_t)sn_ * 200]; }                                          \
    float act = fmaf(rcpf(1.f + __expf(-sce * gg)), sce, ade);                \
    abuf[(S) & 1][wid][kln] = act;                                            \
    FENCE_BAR                                                                 \
    float i_ = abuf[(S) & 1][0][kln];                                         \
    float f_ = abuf[(S) & 1][1][kln];                                         \
    float gt = abuf[(S) & 1][2][kln];                                         \
    float o_ = abuf[(S) & 1][3][kln];                                         \
    cst = fmaf(f_, cst, i_ * gt);                                             \
    float th = fmaf(rcpf(1.f + __expf(-2.f * cst)), 2.f, -1.f);               \
    hv = o_ * th;                                                             \
    hkeep = (t0 + (S) == lastidx) ? hv : hkeep;                               \
}

__global__ __launch_bounds__(256)
__attribute__((amdgpu_waves_per_eu(1, 1)))   // 4 waves -> 1 per SIMD, full budgets
void k2_scan(const int* __restrict__ x, const int* __restrict__ lengths,
             const float* __restrict__ emb_table,
             const float* __restrict__ wsWhh, const float* __restrict__ xp,
             const float* __restrict__ pool,
             const float* __restrict__ W_lin, const float* __restrict__ b_lin,
             float* __restrict__ stH, float* __restrict__ stC, float* __restrict__ lastH,
             float* __restrict__ out, int t0, int t1, int tcAlloc, int fullPool)
{
    const int b   = blockIdx.x, tid = threadIdx.x;
    const int wid = tid >> 6;                  // gate q: 0=i 1=f 2=g 3=o
    const int kln = tid & 63;                  // lane = hidden unit
    const int kc  = (kln < NH) ? kln : NH - 1; // lanes 50-63 shadow unit 49 (harmless dup)

    __shared__ __align__(16) float abuf[2][4][64];  // [parity][gate][lane] acts, 2KB
    __shared__ int xv[NT];                          // fallback epilogue only
    __shared__ float ps[5][52], pm[5][52];          // fallback epilogue only
    __shared__ float rep[160];                      // concat vector

    const int lastidx = min(lengths[b], NT) - 1;
    const int nsteps  = t1 - t0;

    float hv  = (t0 == 0) ? 0.f : stH[b * NH + kc];
    float cst = (t0 == 0) ? 0.f : stC[b * NH + kc];

    // weights: ONE gate row = 13 aligned dwordx4 = 52 VGPRs (fits under the ~132 cap)
    DECLROW(CW)
    LOADROW(CW, wsWhh + ((size_t)wid * NH + kc) * 52)
    asm volatile("s_waitcnt vmcnt(0)" ::: "memory");
    __builtin_amdgcn_sched_barrier(0);

    const float sce = (wid == 2) ? 2.f : 1.f;      // gate g: tanh(x)=2*sigmoid(2x)-1
    const float ade = (wid == 2) ? -1.f : 0.f;     // sigmoid: fma(r,1,0)==r bitwise

    const float* xpb = xp + (size_t)b * tcAlloc * 200 + 4 * kc + wid;
    float xq0 = xpb[0];
    float xq1 = xpb[200];
    float xq2 = xpb[400];
    float xq3 = xpb[600];
    float hkeep = 0.f;

    for (int s4 = 0; s4 < nsteps; s4 += 4) {
        SSTEP(xq0, s4 + 0)
        SSTEP(xq1, s4 + 1)
        SSTEP(xq2, s4 + 2)
        SSTEP(xq3, s4 + 3)
    }

    if (wid == 0 && kln < NH) {
        stH[b * NH + kln] = hv;
        stC[b * NH + kln] = cst;
        if (lastidx >= t0 && lastidx < t1) lastH[b * NH + kln] = hkeep;
    }

    // -------- fused epilogue (final chunk only; t1/fullPool are kernel args -> uniform) ---
    if (t1 == NT) {
        if (fullPool) {
            // O(1): combine 8 per-tile pooling partials computed by k1
            if (tid < NH) {
                const float* poolS = pool;
                const float* poolM = pool + (size_t)NB * 8 * 64;
                float s = 0.f, m = -INFINITY;
                #pragma unroll
                for (int ta = 0; ta < 8; ++ta) {
                    s = s + poolS[((size_t)b * 8 + ta) * 64 + tid];
                    m = fmaxf(m, poolM[((size_t)b * 8 + ta) * 64 + tid]);
                }
                rep[tid]          = (lastidx >= t0) ? hkeep : lastH[b * NH + tid];
                rep[NH + tid]     = s / (float)lengths[b];
                rep[2 * NH + tid] = m;
            }
            __syncthreads();
            if (tid < NC) {
                float acc = b_lin[tid];
                #pragma unroll 5
                for (int j = 0; j < 3 * NH; ++j)
                    acc = fmaf(rep[j], W_lin[tid * 3 * NH + j], acc);
                out[(size_t)b * NC + tid] = acc;
            }
        } else {
            // fallback: R17's full pooling (multi-chunk mode)
            for (int i = tid; i < NT; i += 256) xv[i] = x[(size_t)b * NT + i];
            __syncthreads();
            const int g5 = tid / ND, d5 = tid - g5 * ND;
            if (tid < 250) {
                float s = 0.f, m = -INFINITY;
                #pragma unroll 4
                for (int t = g5; t < NT; t += 5) {
                    float e = emb_table[(size_t)xv[t] * ND + d5];
                    s += e; m = fmaxf(m, e);
                }
                ps[g5][d5] = s; pm[g5][d5] = m;
            }
            __syncthreads();
            if (tid < NH) {
                float s = ps[0][tid] + ps[1][tid] + ps[2][tid] + ps[3][tid] + ps[4][tid];
                float m = fmaxf(fmaxf(fmaxf(pm[0][tid], pm[1][tid]),
                                      fmaxf(pm[2][tid], pm[3][tid])), pm[4][tid]);
                rep[tid]          = (lastidx >= t0) ? hkeep : lastH[b * NH + tid];
                rep[NH + tid]     = s / (float)lengths[b];
                rep[2 * NH + tid] = m;
            }
            __syncthreads();
            if (tid < NC) {
                float acc = b_lin[tid];
                #pragma unroll 5
                for (int j = 0; j < 3 * NH; ++j)
                    acc = fmaf(rep[j], W_lin[tid * 3 * NH + j], acc);
                out[(size_t)b * NC + tid] = acc;
            }
        }
    }
}

extern "C" void kernel_launch(void* const* d_in, const int* in_sizes, int n_in,
                              void* d_out, int out_size, void* d_ws, size_t ws_size,
                              hipStream_t stream) {
    const int*   x     = (const int*)d_in[0];
    const int*   len   = (const int*)d_in[1];
    const float* emb   = (const float*)d_in[3];
    const float* W_ih  = (const float*)d_in[4];
    const float* W_hh  = (const float*)d_in[5];
    const float* b_ih  = (const float*)d_in[6];
    const float* b_hh  = (const float*)d_in[7];
    const float* W_lin = (const float*)d_in[8];
    const float* b_lin = (const float*)d_in[9];
    float* outp = (float*)d_out;

    // ws: [stH][stC][lastH] | @160KB: wsWih, wsWhh | @256KB: pool (1MB) | @1.25MB: xp
    float* stH   = (float*)d_ws;
    float* stC   = stH + NB * NH;
    float* lastH = stC + NB * NH;
    float* wsWih = (float*)((char*)d_ws + 160 * 1024);
    float* wsWhh = wsWih + 200 * 52;
    float* pool  = (float*)((char*)d_ws + 256 * 1024);       // 2*256*8*64*4 = 1MB exactly
    const size_t xpOff = 256 * 1024 + 1024 * 1024;
    float* xp = (float*)((char*)d_ws + xpOff);

    size_t avail = (ws_size > xpOff + 8192) ? ws_size - xpOff - 8192 : 0;
    int tc = (int)(avail / ((size_t)NB * 200 * sizeof(float)));
    tc &= ~3;                 // chunks are multiples of 4
    if (tc > NT) tc = NT;
    if (tc < 4)  tc = 4;
    const int fullPool = (tc >= NT) ? 1 : 0;

    hipLaunchKernelGGL(k0_prep, dim3(82), dim3(256), 0, stream, W_hh, W_ih, wsWih, wsWhh);

    for (int t0 = 0; t0 < NT; t0 += tc) {
        const int t1 = min(NT, t0 + tc);
        const int tiles = (t1 - t0 + 63) / 64;
        hipLaunchKernelGGL(k1_xproj, dim3(NB * tiles), dim3(256), 0, stream,
                           x, len, emb, wsWih, b_ih, b_hh, xp, pool,
                           t0, t1, tiles, tc, fullPool);
        hipLaunchKernelGGL(k2_scan, dim3(NB), dim3(256), 0, stream,
                           x, len, emb, wsWhh, xp, pool, W_lin, b_lin,
                           stH, stC, lastH, outp, t0, t1, tc, fullPool);
    }
}